// Round 5
// baseline (1296.049 us; speedup 1.0000x reference)
//
#include <hip/hip_runtime.h>

#define NN 100000
#define NE 1600000
#define NB 64
#define DIN 78
#define DH 128
#define SD 768
#define FD 256
#define SCAN_NBLK 98   // ceil(NN/1024)

// 1/sqrt(1 + 1e-5)
#define BN_SCALE 0.9999950000374997f

// ================= CSR build =================
__global__ void zero_counts(int* __restrict__ counts) {
    int i = blockIdx.x * 1024 + threadIdx.x;
    if (i < NN) counts[i] = 0;
}

__global__ void hist_kernel(const int* __restrict__ dst, int* __restrict__ counts) {
    int e = blockIdx.x * 256 + threadIdx.x;
    if (e < NE) atomicAdd(&counts[dst[e]], 1);
}

// per-block exclusive scan (1024 elems/block) + block sums
__global__ __launch_bounds__(1024) void scan1(const int* __restrict__ counts,
                                              int* __restrict__ excl,
                                              int* __restrict__ bsums) {
    __shared__ int tmp[1024];
    int tid = threadIdx.x;
    int i = blockIdx.x * 1024 + tid;
    int v = (i < NN) ? counts[i] : 0;
    tmp[tid] = v;
    __syncthreads();
#pragma unroll
    for (int off = 1; off < 1024; off <<= 1) {
        int t = (tid >= off) ? tmp[tid - off] : 0;
        __syncthreads();
        tmp[tid] += t;
        __syncthreads();
    }
    if (i < NN) excl[i] = tmp[tid] - v;
    if (tid == 1023) bsums[blockIdx.x] = tmp[1023];
}

// exclusive scan of the block sums (single block, nb <= 128)
__global__ __launch_bounds__(128) void scan2(int* __restrict__ bsums, int nb) {
    __shared__ int tmp[128];
    int tid = threadIdx.x;
    int v = (tid < nb) ? bsums[tid] : 0;
    tmp[tid] = v;
    __syncthreads();
#pragma unroll
    for (int off = 1; off < 128; off <<= 1) {
        int t = (tid >= off) ? tmp[tid - off] : 0;
        __syncthreads();
        tmp[tid] += t;
        __syncthreads();
    }
    if (tid < nb) bsums[tid] = tmp[tid] - v;
}

__global__ void scan3(const int* __restrict__ excl, const int* __restrict__ bsums,
                      int* __restrict__ offsets, int* __restrict__ cursor) {
    int i = blockIdx.x * 1024 + threadIdx.x;
    if (i < NN) {
        int v = excl[i] + bsums[blockIdx.x];
        offsets[i] = v;
        cursor[i] = v;
    }
}

__global__ void scatter_kernel(const int* __restrict__ src, const int* __restrict__ dst,
                               int* __restrict__ cursor, int* __restrict__ eidx) {
    int e = blockIdx.x * 256 + threadIdx.x;
    if (e < NE) {
        int p = atomicAdd(&cursor[dst[e]], 1);
        eidx[p] = src[e];
    }
}

// ================= gather-based aggregation =================
// z[n] = h[n] + sum_{e: dst=n} h[src[e]]
// D=128: one wave per node; half-wave (32 lanes x float4 = 512B) per neighbor row,
// so each wave streams 2 neighbor rows per iteration.
__global__ __launch_bounds__(256) void agg_csr128(const float* __restrict__ h,
                                                  const int* __restrict__ off,
                                                  const int* __restrict__ cnt,
                                                  const int* __restrict__ eidx,
                                                  float* __restrict__ z) {
    int node = blockIdx.x * 4 + (threadIdx.x >> 6);
    if (node >= NN) return;
    int lane = threadIdx.x & 63;
    int half = lane >> 5;            // neighbor parity handled by this half-wave
    int col = (lane & 31) << 2;      // float4 column
    int start = off[node], deg = cnt[node];
    float4 sum = make_float4(0.f, 0.f, 0.f, 0.f);
    if (half == 0) sum = *(const float4*)&h[(size_t)node * DH + col];
    for (int base = 0; base < deg; base += 64) {
        int rem = deg - base;
        int m = rem < 64 ? rem : 64;
        int ev = (lane < m) ? eidx[start + base + lane] : 0;
#pragma unroll 2
        for (int j = half; j < m; j += 2) {
            int s = __shfl(ev, j);
            float4 v = *(const float4*)&h[(size_t)s * DH + col];
            sum.x += v.x; sum.y += v.y; sum.z += v.z; sum.w += v.w;
        }
    }
    sum.x += __shfl_xor(sum.x, 32);
    sum.y += __shfl_xor(sum.y, 32);
    sum.z += __shfl_xor(sum.z, 32);
    sum.w += __shfl_xor(sum.w, 32);
    if (half == 0) *(float4*)&z[(size_t)node * DH + col] = sum;
}

// D=78 variant: lanes 0..38 hold float2 columns
__global__ __launch_bounds__(256) void agg_csr78(const float* __restrict__ h,
                                                 const int* __restrict__ off,
                                                 const int* __restrict__ cnt,
                                                 const int* __restrict__ eidx,
                                                 float* __restrict__ z) {
    int node = blockIdx.x * 4 + (threadIdx.x >> 6);
    if (node >= NN) return;
    int lane = threadIdx.x & 63;
    bool act = lane < 39;
    int col = lane * 2;
    int start = off[node], deg = cnt[node];
    float2 sum = make_float2(0.f, 0.f);
    if (act) sum = *(const float2*)&h[(size_t)node * DIN + col];
    for (int base = 0; base < deg; base += 64) {
        int rem = deg - base;
        int m = rem < 64 ? rem : 64;
        int ev = (lane < m) ? eidx[start + base + lane] : 0;
#pragma unroll 4
        for (int j = 0; j < m; ++j) {
            int s = __shfl(ev, j);
            if (act) {
                float2 v = *(const float2*)&h[(size_t)s * DIN + col];
                sum.x += v.x;
                sum.y += v.y;
            }
        }
    }
    if (act) *(float2*)&z[(size_t)node * DIN + col] = sum;
}

// ================= GEMM: C[N,128] = epi(A[N,K] @ W[K,128]) =================
// 128x128 tile, BK=32, 256 threads, 8x8 acc per thread.
// EPI 0: relu(acc + bias)
// EPI 1: relu((acc + bias) * (g*BN_SCALE) + bb)
template <int K, int EPI>
__global__ __launch_bounds__(256) void gemm_epi(
        const float* __restrict__ A, const float* __restrict__ W,
        const float* __restrict__ bias, const float* __restrict__ g,
        const float* __restrict__ bb, float* __restrict__ C, int nrows) {
    constexpr int BM = 128, BN = 128, BK = 32;
    __shared__ float As[BK][BM];   // transposed: As[k][row]
    __shared__ float Bs[BK][BN];
    const int tid = threadIdx.x;
    const int tx = tid & 15;       // col group (8 cols)
    const int ty = tid >> 4;       // row group (8 rows)
    const int r0 = blockIdx.x * BM;

    float acc[8][8];
#pragma unroll
    for (int i = 0; i < 8; ++i)
#pragma unroll
        for (int j = 0; j < 8; ++j) acc[i][j] = 0.f;

    const int tr = tid >> 1;       // 0..127 : A row within tile
    const int l2 = tid & 1;
    const int arow = r0 + tr;
    const bool aok = arow < nrows;

    for (int kt = 0; kt < K; kt += BK) {
        const int ksz = (K - kt < BK) ? (K - kt) : BK;
        // B tile: rows kt..kt+ksz-1 of W, full 128 wide, float4 loads
        for (int i = tid; i < ksz * (BN / 4); i += 256) {
            int kk = i >> 5;
            int cc = (i & 31) << 2;
            *(float4*)&Bs[kk][cc] = *(const float4*)&W[(size_t)(kt + kk) * BN + cc];
        }
        // A tile transposed: each thread covers one row, alternating k
        for (int k = l2; k < ksz; k += 2)
            As[k][tr] = aok ? A[(size_t)arow * K + kt + k] : 0.f;
        __syncthreads();

        if (ksz == BK) {
#pragma unroll
            for (int k = 0; k < BK; ++k) {
                float4 a0 = *(const float4*)&As[k][ty * 8];
                float4 a1 = *(const float4*)&As[k][ty * 8 + 4];
                float4 b0 = *(const float4*)&Bs[k][tx * 8];
                float4 b1 = *(const float4*)&Bs[k][tx * 8 + 4];
                float av[8] = {a0.x, a0.y, a0.z, a0.w, a1.x, a1.y, a1.z, a1.w};
                float bv[8] = {b0.x, b0.y, b0.z, b0.w, b1.x, b1.y, b1.z, b1.w};
#pragma unroll
                for (int i = 0; i < 8; ++i)
#pragma unroll
                    for (int j = 0; j < 8; ++j)
                        acc[i][j] = fmaf(av[i], bv[j], acc[i][j]);
            }
        } else {
            for (int k = 0; k < ksz; ++k) {
                float4 a0 = *(const float4*)&As[k][ty * 8];
                float4 a1 = *(const float4*)&As[k][ty * 8 + 4];
                float4 b0 = *(const float4*)&Bs[k][tx * 8];
                float4 b1 = *(const float4*)&Bs[k][tx * 8 + 4];
                float av[8] = {a0.x, a0.y, a0.z, a0.w, a1.x, a1.y, a1.z, a1.w};
                float bv[8] = {b0.x, b0.y, b0.z, b0.w, b1.x, b1.y, b1.z, b1.w};
#pragma unroll
                for (int i = 0; i < 8; ++i)
#pragma unroll
                    for (int j = 0; j < 8; ++j)
                        acc[i][j] = fmaf(av[i], bv[j], acc[i][j]);
            }
        }
        __syncthreads();
    }

#pragma unroll
    for (int i = 0; i < 8; ++i) {
        int row = r0 + ty * 8 + i;
        if (row >= nrows) continue;
        float out[8];
#pragma unroll
        for (int j = 0; j < 8; ++j) {
            int col = tx * 8 + j;
            float v = acc[i][j] + bias[col];
            if constexpr (EPI == 1) {
                v = v * (g[col] * BN_SCALE) + bb[col];
            }
            out[j] = fmaxf(v, 0.f);
        }
        *(float4*)&C[(size_t)row * BN + tx * 8] = *(float4*)&out[0];
        *(float4*)&C[(size_t)row * BN + tx * 8 + 4] = *(float4*)&out[4];
    }
}

// ================= global mean pool =================
__device__ __forceinline__ int lower_bound_i(const int* a, int n, int v) {
    int lo = 0, hi = n;
    while (lo < hi) {
        int m = (lo + hi) >> 1;
        if (a[m] < v) lo = m + 1; else hi = m;
    }
    return lo;
}

__global__ __launch_bounds__(1024) void pool_kernel(const float* __restrict__ h,
                                                    const int* __restrict__ batch,
                                                    float* __restrict__ gf) {
    int b = blockIdx.x;
    int f = threadIdx.x & 127;
    int chunk = threadIdx.x >> 7;   // 0..7
    __shared__ float part[8][DH];
    int lo = lower_bound_i(batch, NN, b);
    int hi = lower_bound_i(batch, NN, b + 1);
    float sum = 0.f;
    for (int i = lo + chunk; i < hi; i += 8) sum += h[(size_t)i * DH + f];
    part[chunk][f] = sum;
    __syncthreads();
    if (chunk == 0) {
        float s = part[0][f] + part[1][f] + part[2][f] + part[3][f] +
                  part[4][f] + part[5][f] + part[6][f] + part[7][f];
        int cnt = hi - lo;
        gf[b * DH + f] = s / (float)(cnt > 0 ? cnt : 1);
    }
}

// ================= fusion + attention + classifier =================
__global__ __launch_bounds__(256) void fusion_kernel(
        const float* __restrict__ sem, const float* __restrict__ gf,
        const float* __restrict__ Ws, const float* __restrict__ bs,
        const float* __restrict__ Wg, const float* __restrict__ bg,
        const float* __restrict__ Wq, const float* __restrict__ Wk,
        const float* __restrict__ Wv,
        const float* __restrict__ Wc1, const float* __restrict__ bc1,
        const float* __restrict__ Wc2, const float* __restrict__ bc2,
        float* __restrict__ out) {
    int b = blockIdx.x;
    int c = threadIdx.x;  // 256
    __shared__ float tok[2][FD];
    __shared__ float qv[6][FD];
    __shared__ float att[4];
    __shared__ float fused[FD];
    __shared__ float c1[FD / 2];

    {
        float acc = bs[c];
        const float* sr = &sem[(size_t)b * SD];
#pragma unroll 8
        for (int k = 0; k < SD; ++k) acc = fmaf(sr[k], Ws[(size_t)k * FD + c], acc);
        tok[0][c] = acc;
    }
    {
        float acc = bg[c];
        const float* gr = &gf[(size_t)b * DH];
#pragma unroll 8
        for (int k = 0; k < DH; ++k) acc = fmaf(gr[k], Wg[(size_t)k * FD + c], acc);
        tok[1][c] = acc;
    }
    __syncthreads();

#pragma unroll
    for (int t = 0; t < 2; ++t) {
        float qa = 0.f, ka = 0.f, va = 0.f;
#pragma unroll 4
        for (int k = 0; k < FD; ++k) {
            float tv = tok[t][k];
            qa = fmaf(tv, Wq[(size_t)k * FD + c], qa);
            ka = fmaf(tv, Wk[(size_t)k * FD + c], ka);
            va = fmaf(tv, Wv[(size_t)k * FD + c], va);
        }
        qv[0 + t][c] = qa;
        qv[2 + t][c] = ka;
        qv[4 + t][c] = va;
    }
    __syncthreads();

    if (c < 4) {
        int qi = c >> 1, ki = c & 1;
        float s = 0.f;
        for (int k = 0; k < FD; ++k) s += qv[qi][k] * qv[2 + ki][k];
        att[c] = s * (1.0f / 16.0f);
    }
    __syncthreads();
    if (c < 2) {
        float a0 = att[c * 2], a1 = att[c * 2 + 1];
        float m = fmaxf(a0, a1);
        float e0 = __expf(a0 - m), e1 = __expf(a1 - m);
        float inv = 1.f / (e0 + e1);
        att[c * 2] = e0 * inv;
        att[c * 2 + 1] = e1 * inv;
    }
    __syncthreads();

    fused[c] = 0.5f * (att[0] * qv[4][c] + att[1] * qv[5][c] +
                       att[2] * qv[4][c] + att[3] * qv[5][c]);
    __syncthreads();

    if (c < FD / 2) {
        float acc = bc1[c];
#pragma unroll 4
        for (int k = 0; k < FD; ++k) acc = fmaf(fused[k], Wc1[(size_t)k * (FD / 2) + c], acc);
        c1[c] = fmaxf(acc, 0.f);
    }
    __syncthreads();

    if (c < 2) {
        float acc = bc2[c];
        for (int k = 0; k < FD / 2; ++k) acc = fmaf(c1[k], Wc2[(size_t)k * 2 + c], acc);
        out[b * 2 + c] = acc;
    }
}

// ================= launch =================
extern "C" void kernel_launch(void* const* d_in, const int* in_sizes, int n_in,
                              void* d_out, int out_size, void* d_ws, size_t ws_size,
                              hipStream_t stream) {
    const float* sem   = (const float*)d_in[0];
    const float* x     = (const float*)d_in[1];
    const int*   ei    = (const int*)d_in[2];
    const int*   batch = (const int*)d_in[3];
    const int* src = ei;
    const int* dst = ei + NE;

    const float* c1W1 = (const float*)d_in[4];
    const float* c1b1 = (const float*)d_in[5];
    const float* c1W2 = (const float*)d_in[6];
    const float* c1b2 = (const float*)d_in[7];
    const float* c2W1 = (const float*)d_in[8];
    const float* c2b1 = (const float*)d_in[9];
    const float* c2W2 = (const float*)d_in[10];
    const float* c2b2 = (const float*)d_in[11];
    const float* c3W1 = (const float*)d_in[12];
    const float* c3b1 = (const float*)d_in[13];
    const float* c3W2 = (const float*)d_in[14];
    const float* c3b2 = (const float*)d_in[15];
    const float* bn1g = (const float*)d_in[16];
    const float* bn1b = (const float*)d_in[17];
    const float* bn2g = (const float*)d_in[18];
    const float* bn2b = (const float*)d_in[19];
    const float* bn3g = (const float*)d_in[20];
    const float* bn3b = (const float*)d_in[21];
    const float* Ws   = (const float*)d_in[22];
    const float* bs_  = (const float*)d_in[23];
    const float* Wg   = (const float*)d_in[24];
    const float* bg   = (const float*)d_in[25];
    const float* Wq   = (const float*)d_in[26];
    const float* Wk   = (const float*)d_in[27];
    const float* Wv   = (const float*)d_in[28];
    const float* Wc1  = (const float*)d_in[29];
    const float* bc1  = (const float*)d_in[30];
    const float* Wc2  = (const float*)d_in[31];
    const float* bc2  = (const float*)d_in[32];

    // workspace layout
    float* P  = (float*)d_ws;
    float* Q  = P + (size_t)NN * DH;
    float* R  = Q + (size_t)NN * DH;
    float* gf = R + (size_t)NN * DH;
    int* counts  = (int*)(gf + (size_t)NB * DH);
    int* offsets = counts + NN;
    int* cursor  = offsets + NN;
    int* excl    = cursor + NN;
    int* bsums   = excl + NN;
    int* eidx    = bsums + 128;

    const int gemm_grid = (NN + 127) / 128;
    const int agg_grid  = (NN + 3) / 4;
    const int edge_grid = (NE + 255) / 256;

    // ---- CSR build (once per call, reused by all 3 layers) ----
    zero_counts<<<SCAN_NBLK, 1024, 0, stream>>>(counts);
    hist_kernel<<<edge_grid, 256, 0, stream>>>(dst, counts);
    scan1<<<SCAN_NBLK, 1024, 0, stream>>>(counts, excl, bsums);
    scan2<<<1, 128, 0, stream>>>(bsums, SCAN_NBLK);
    scan3<<<SCAN_NBLK, 1024, 0, stream>>>(excl, bsums, offsets, cursor);
    scatter_kernel<<<edge_grid, 256, 0, stream>>>(src, dst, cursor, eidx);

    // ---- layer 1 (input dim 78) ----
    agg_csr78<<<agg_grid, 256, 0, stream>>>(x, offsets, counts, eidx, P);
    gemm_epi<DIN, 0><<<gemm_grid, 256, 0, stream>>>(P, c1W1, c1b1, nullptr, nullptr, Q, NN);
    gemm_epi<DH, 1><<<gemm_grid, 256, 0, stream>>>(Q, c1W2, c1b2, bn1g, bn1b, R, NN);

    // ---- layer 2 ----
    agg_csr128<<<agg_grid, 256, 0, stream>>>(R, offsets, counts, eidx, P);
    gemm_epi<DH, 0><<<gemm_grid, 256, 0, stream>>>(P, c2W1, c2b1, nullptr, nullptr, Q, NN);
    gemm_epi<DH, 1><<<gemm_grid, 256, 0, stream>>>(Q, c2W2, c2b2, bn2g, bn2b, R, NN);

    // ---- layer 3 ----
    agg_csr128<<<agg_grid, 256, 0, stream>>>(R, offsets, counts, eidx, P);
    gemm_epi<DH, 0><<<gemm_grid, 256, 0, stream>>>(P, c3W1, c3b1, nullptr, nullptr, Q, NN);
    gemm_epi<DH, 1><<<gemm_grid, 256, 0, stream>>>(Q, c3W2, c3b2, bn3g, bn3b, R, NN);

    // ---- pool + fusion ----
    pool_kernel<<<NB, 1024, 0, stream>>>(R, batch, gf);
    fusion_kernel<<<NB, 256, 0, stream>>>(sem, gf, Ws, bs_, Wg, bg, Wq, Wk, Wv,
                                          Wc1, bc1, Wc2, bc2, (float*)d_out);
}

// Round 6
// 1223.450 us; speedup vs baseline: 1.0593x; 1.0593x over previous
//
#include <hip/hip_runtime.h>

#define NN 100000
#define NE 1600000
#define NB 64
#define DIN 78
#define DH 128
#define SD 768
#define FD 256
#define SCAN_NBLK 98   // ceil(NN/1024)

// 1/sqrt(1 + 1e-5)
#define BN_SCALE 0.9999950000374997f

// ================= CSR build =================
__global__ void zero_counts(int* __restrict__ counts) {
    int i = blockIdx.x * 1024 + threadIdx.x;
    if (i < NN) counts[i] = 0;
}

__global__ void hist_kernel(const int* __restrict__ dst, int* __restrict__ counts) {
    int e = blockIdx.x * 256 + threadIdx.x;
    if (e < NE) atomicAdd(&counts[dst[e]], 1);
}

// per-block exclusive scan (1024 elems/block) + block sums
__global__ __launch_bounds__(1024) void scan1(const int* __restrict__ counts,
                                              int* __restrict__ excl,
                                              int* __restrict__ bsums) {
    __shared__ int tmp[1024];
    int tid = threadIdx.x;
    int i = blockIdx.x * 1024 + tid;
    int v = (i < NN) ? counts[i] : 0;
    tmp[tid] = v;
    __syncthreads();
#pragma unroll
    for (int off = 1; off < 1024; off <<= 1) {
        int t = (tid >= off) ? tmp[tid - off] : 0;
        __syncthreads();
        tmp[tid] += t;
        __syncthreads();
    }
    if (i < NN) excl[i] = tmp[tid] - v;
    if (tid == 1023) bsums[blockIdx.x] = tmp[1023];
}

// exclusive scan of the block sums (single block, nb <= 128)
__global__ __launch_bounds__(128) void scan2(int* __restrict__ bsums, int nb) {
    __shared__ int tmp[128];
    int tid = threadIdx.x;
    int v = (tid < nb) ? bsums[tid] : 0;
    tmp[tid] = v;
    __syncthreads();
#pragma unroll
    for (int off = 1; off < 128; off <<= 1) {
        int t = (tid >= off) ? tmp[tid - off] : 0;
        __syncthreads();
        tmp[tid] += t;
        __syncthreads();
    }
    if (tid < nb) bsums[tid] = tmp[tid] - v;
}

__global__ void scan3(const int* __restrict__ excl, const int* __restrict__ bsums,
                      int* __restrict__ offsets, int* __restrict__ cursor) {
    int i = blockIdx.x * 1024 + threadIdx.x;
    if (i < NN) {
        int v = excl[i] + bsums[blockIdx.x];
        offsets[i] = v;
        cursor[i] = v;
    }
}

__global__ void scatter_kernel(const int* __restrict__ src, const int* __restrict__ dst,
                               int* __restrict__ cursor, int* __restrict__ eidx) {
    int e = blockIdx.x * 256 + threadIdx.x;
    if (e < NE) {
        int p = atomicAdd(&cursor[dst[e]], 1);
        eidx[p] = src[e];
    }
}

// ================= gather-based aggregation =================
// z[n] = h[n] + sum_{e: dst=n} h[src[e]]
// D=128: one wave per node; half-wave (32 lanes x float4 = 512B) per neighbor row,
// so each wave streams 2 neighbor rows per iteration.
__global__ __launch_bounds__(256) void agg_csr128(const float* __restrict__ h,
                                                  const int* __restrict__ off,
                                                  const int* __restrict__ cnt,
                                                  const int* __restrict__ eidx,
                                                  float* __restrict__ z) {
    int node = blockIdx.x * 4 + (threadIdx.x >> 6);
    if (node >= NN) return;
    int lane = threadIdx.x & 63;
    int half = lane >> 5;            // neighbor parity handled by this half-wave
    int col = (lane & 31) << 2;      // float4 column
    int start = off[node], deg = cnt[node];
    float4 sum = make_float4(0.f, 0.f, 0.f, 0.f);
    if (half == 0) sum = *(const float4*)&h[(size_t)node * DH + col];
    for (int base = 0; base < deg; base += 64) {
        int rem = deg - base;
        int m = rem < 64 ? rem : 64;
        int ev = (lane < m) ? eidx[start + base + lane] : 0;
#pragma unroll 2
        for (int j = half; j < m; j += 2) {
            int s = __shfl(ev, j);
            float4 v = *(const float4*)&h[(size_t)s * DH + col];
            sum.x += v.x; sum.y += v.y; sum.z += v.z; sum.w += v.w;
        }
    }
    sum.x += __shfl_xor(sum.x, 32);
    sum.y += __shfl_xor(sum.y, 32);
    sum.z += __shfl_xor(sum.z, 32);
    sum.w += __shfl_xor(sum.w, 32);
    if (half == 0) *(float4*)&z[(size_t)node * DH + col] = sum;
}

// D=78 variant: lanes 0..38 hold float2 columns
__global__ __launch_bounds__(256) void agg_csr78(const float* __restrict__ h,
                                                 const int* __restrict__ off,
                                                 const int* __restrict__ cnt,
                                                 const int* __restrict__ eidx,
                                                 float* __restrict__ z) {
    int node = blockIdx.x * 4 + (threadIdx.x >> 6);
    if (node >= NN) return;
    int lane = threadIdx.x & 63;
    bool act = lane < 39;
    int col = lane * 2;
    int start = off[node], deg = cnt[node];
    float2 sum = make_float2(0.f, 0.f);
    if (act) sum = *(const float2*)&h[(size_t)node * DIN + col];
    for (int base = 0; base < deg; base += 64) {
        int rem = deg - base;
        int m = rem < 64 ? rem : 64;
        int ev = (lane < m) ? eidx[start + base + lane] : 0;
#pragma unroll 4
        for (int j = 0; j < m; ++j) {
            int s = __shfl(ev, j);
            if (act) {
                float2 v = *(const float2*)&h[(size_t)s * DIN + col];
                sum.x += v.x;
                sum.y += v.y;
            }
        }
    }
    if (act) *(float2*)&z[(size_t)node * DIN + col] = sum;
}

// ================= GEMM: C[N,128] = epi(A[N,K] @ W[K,128]) =================
// 128x128 tile, BK=32, 256 threads, 8x8 acc per thread.
// EPI 0: relu(acc + bias)
// EPI 1: relu((acc + bias) * (g*BN_SCALE) + bb)
template <int K, int EPI>
__global__ __launch_bounds__(256) void gemm_epi(
        const float* __restrict__ A, const float* __restrict__ W,
        const float* __restrict__ bias, const float* __restrict__ g,
        const float* __restrict__ bb, float* __restrict__ C, int nrows) {
    constexpr int BM = 128, BN = 128, BK = 32;
    __shared__ float As[BK][BM];   // transposed: As[k][row]
    __shared__ float Bs[BK][BN];
    const int tid = threadIdx.x;
    const int tx = tid & 15;       // col group (8 cols)
    const int ty = tid >> 4;       // row group (8 rows)
    const int r0 = blockIdx.x * BM;

    float acc[8][8];
#pragma unroll
    for (int i = 0; i < 8; ++i)
#pragma unroll
        for (int j = 0; j < 8; ++j) acc[i][j] = 0.f;

    const int tr = tid >> 1;       // 0..127 : A row within tile
    const int l2 = tid & 1;
    const int arow = r0 + tr;
    const bool aok = arow < nrows;

    for (int kt = 0; kt < K; kt += BK) {
        const int ksz = (K - kt < BK) ? (K - kt) : BK;
        // B tile: rows kt..kt+ksz-1 of W, full 128 wide, float4 loads
        for (int i = tid; i < ksz * (BN / 4); i += 256) {
            int kk = i >> 5;
            int cc = (i & 31) << 2;
            *(float4*)&Bs[kk][cc] = *(const float4*)&W[(size_t)(kt + kk) * BN + cc];
        }
        // A tile transposed: each thread covers one row, alternating k
        for (int k = l2; k < ksz; k += 2)
            As[k][tr] = aok ? A[(size_t)arow * K + kt + k] : 0.f;
        __syncthreads();

        if (ksz == BK) {
#pragma unroll
            for (int k = 0; k < BK; ++k) {
                float4 a0 = *(const float4*)&As[k][ty * 8];
                float4 a1 = *(const float4*)&As[k][ty * 8 + 4];
                float4 b0 = *(const float4*)&Bs[k][tx * 8];
                float4 b1 = *(const float4*)&Bs[k][tx * 8 + 4];
                float av[8] = {a0.x, a0.y, a0.z, a0.w, a1.x, a1.y, a1.z, a1.w};
                float bv[8] = {b0.x, b0.y, b0.z, b0.w, b1.x, b1.y, b1.z, b1.w};
#pragma unroll
                for (int i = 0; i < 8; ++i)
#pragma unroll
                    for (int j = 0; j < 8; ++j)
                        acc[i][j] = fmaf(av[i], bv[j], acc[i][j]);
            }
        } else {
            for (int k = 0; k < ksz; ++k) {
                float4 a0 = *(const float4*)&As[k][ty * 8];
                float4 a1 = *(const float4*)&As[k][ty * 8 + 4];
                float4 b0 = *(const float4*)&Bs[k][tx * 8];
                float4 b1 = *(const float4*)&Bs[k][tx * 8 + 4];
                float av[8] = {a0.x, a0.y, a0.z, a0.w, a1.x, a1.y, a1.z, a1.w};
                float bv[8] = {b0.x, b0.y, b0.z, b0.w, b1.x, b1.y, b1.z, b1.w};
#pragma unroll
                for (int i = 0; i < 8; ++i)
#pragma unroll
                    for (int j = 0; j < 8; ++j)
                        acc[i][j] = fmaf(av[i], bv[j], acc[i][j]);
            }
        }
        __syncthreads();
    }

#pragma unroll
    for (int i = 0; i < 8; ++i) {
        int row = r0 + ty * 8 + i;
        if (row >= nrows) continue;
        float out[8];
#pragma unroll
        for (int j = 0; j < 8; ++j) {
            int col = tx * 8 + j;
            float v = acc[i][j] + bias[col];
            if constexpr (EPI == 1) {
                v = v * (g[col] * BN_SCALE) + bb[col];
            }
            out[j] = fmaxf(v, 0.f);
        }
        *(float4*)&C[(size_t)row * BN + tx * 8] = *(float4*)&out[0];
        *(float4*)&C[(size_t)row * BN + tx * 8 + 4] = *(float4*)&out[4];
    }
}

// ================= global mean pool =================
__device__ __forceinline__ int lower_bound_i(const int* a, int n, int v) {
    int lo = 0, hi = n;
    while (lo < hi) {
        int m = (lo + hi) >> 1;
        if (a[m] < v) lo = m + 1; else hi = m;
    }
    return lo;
}

__global__ __launch_bounds__(1024) void pool_kernel(const float* __restrict__ h,
                                                    const int* __restrict__ batch,
                                                    float* __restrict__ gf) {
    int b = blockIdx.x;
    int f = threadIdx.x & 127;
    int chunk = threadIdx.x >> 7;   // 0..7
    __shared__ float part[8][DH];
    int lo = lower_bound_i(batch, NN, b);
    int hi = lower_bound_i(batch, NN, b + 1);
    float sum = 0.f;
    for (int i = lo + chunk; i < hi; i += 8) sum += h[(size_t)i * DH + f];
    part[chunk][f] = sum;
    __syncthreads();
    if (chunk == 0) {
        float s = part[0][f] + part[1][f] + part[2][f] + part[3][f] +
                  part[4][f] + part[5][f] + part[6][f] + part[7][f];
        int cnt = hi - lo;
        gf[b * DH + f] = s / (float)(cnt > 0 ? cnt : 1);
    }
}

// ================= fusion + attention + classifier =================
// One block per graph, 1024 threads, 4-way split-K + LDS reduce.
__global__ __launch_bounds__(1024) void fusion_kernel(
        const float* __restrict__ sem, const float* __restrict__ gf,
        const float* __restrict__ Ws, const float* __restrict__ bs,
        const float* __restrict__ Wg, const float* __restrict__ bg,
        const float* __restrict__ Wq, const float* __restrict__ Wk,
        const float* __restrict__ Wv,
        const float* __restrict__ Wc1, const float* __restrict__ bc1,
        const float* __restrict__ Wc2, const float* __restrict__ bc2,
        float* __restrict__ out) {
    int b = blockIdx.x;
    int tid = threadIdx.x;      // 1024
    int c = tid & 255;
    int kc = tid >> 8;          // 0..3
    __shared__ float tok[2][FD];
    __shared__ float part[4][FD];
    __shared__ float qv[6][FD]; // q0 q1 k0 k1 v0 v1
    __shared__ float att[4];
    __shared__ float fused[FD];
    __shared__ float c1s[FD / 2];

    // ---- token 0: semantic projection, K=768 (192 per kc) ----
    {
        const float* sr = &sem[(size_t)b * SD];
        float acc = 0.f;
#pragma unroll 8
        for (int k = kc * 192; k < (kc + 1) * 192; ++k)
            acc = fmaf(sr[k], Ws[(size_t)k * FD + c], acc);
        part[kc][c] = acc;
    }
    __syncthreads();
    if (kc == 0)
        tok[0][c] = part[0][c] + part[1][c] + part[2][c] + part[3][c] + bs[c];
    __syncthreads();

    // ---- token 1: graph projection, K=128 (32 per kc) ----
    {
        const float* gr = &gf[(size_t)b * DH];
        float acc = 0.f;
#pragma unroll 8
        for (int k = kc * 32; k < (kc + 1) * 32; ++k)
            acc = fmaf(gr[k], Wg[(size_t)k * FD + c], acc);
        part[kc][c] = acc;
    }
    __syncthreads();
    if (kc == 0)
        tok[1][c] = part[0][c] + part[1][c] + part[2][c] + part[3][c] + bg[c];
    __syncthreads();

    // ---- q,k,v for both tokens: 6 matvecs K=256 (64 per kc) ----
    // qv index: 0=q0 1=q1 2=k0 3=k1 4=v0 5=v1
#pragma unroll
    for (int m = 0; m < 6; ++m) {
        const float* Wm = (m < 2) ? Wq : ((m < 4) ? Wk : Wv);
        int t = m & 1;
        float acc = 0.f;
#pragma unroll 8
        for (int k = kc * 64; k < (kc + 1) * 64; ++k)
            acc = fmaf(tok[t][k], Wm[(size_t)k * FD + c], acc);
        part[kc][c] = acc;
        __syncthreads();
        if (kc == 0)
            qv[m][c] = part[0][c] + part[1][c] + part[2][c] + part[3][c];
        __syncthreads();
    }

    // ---- scores: 4 dot-products (one wave each), shfl butterfly ----
    if (tid < 256) {
        int w = tid >> 6;       // 0..3 : (qi,ki) pair
        int lane = tid & 63;
        int qi = w >> 1, ki = w & 1;
        float s = 0.f;
#pragma unroll
        for (int k = lane; k < FD; k += 64) s += qv[qi][k] * qv[2 + ki][k];
#pragma unroll
        for (int d = 1; d < 64; d <<= 1) s += __shfl_xor(s, d);
        if (lane == 0) att[w] = s * (1.0f / 16.0f);
    }
    __syncthreads();
    if (tid < 2) {
        float a0 = att[tid * 2], a1 = att[tid * 2 + 1];
        float mx = fmaxf(a0, a1);
        float e0 = __expf(a0 - mx), e1 = __expf(a1 - mx);
        float inv = 1.f / (e0 + e1);
        att[tid * 2] = e0 * inv;
        att[tid * 2 + 1] = e1 * inv;
    }
    __syncthreads();

    // ---- fused = mean over q of att@v ----
    if (kc == 0)
        fused[c] = 0.5f * ((att[0] + att[2]) * qv[4][c] + (att[1] + att[3]) * qv[5][c]);
    __syncthreads();

    // ---- classifier layer 1: 128 outputs, K=256 (64 per split) ----
    {
        float* pf = &part[0][0];   // flat [1024]
        int cc = tid & 127;
        int k2 = tid >> 7;          // 0..7
        float acc = 0.f;
#pragma unroll 8
        for (int k = k2 * 32; k < (k2 + 1) * 32; ++k)
            acc = fmaf(fused[k], Wc1[(size_t)k * (FD / 2) + cc], acc);
        pf[tid] = acc;
        __syncthreads();
        if (tid < 128) {
            float s = 0.f;
#pragma unroll
            for (int j = 0; j < 8; ++j) s += pf[j * 128 + tid];
            c1s[tid] = fmaxf(s + bc1[tid], 0.f);
        }
    }
    __syncthreads();

    // ---- classifier layer 2: 2 outputs, K=128 (one wave each) ----
    if (tid < 128) {
        int w = tid >> 6;       // output index
        int lane = tid & 63;
        float s = c1s[lane] * Wc2[(size_t)lane * 2 + w] +
                  c1s[lane + 64] * Wc2[(size_t)(lane + 64) * 2 + w];
#pragma unroll
        for (int d = 1; d < 64; d <<= 1) s += __shfl_xor(s, d);
        if (lane == 0) out[b * 2 + w] = s + bc2[w];
    }
}

// ================= launch =================
extern "C" void kernel_launch(void* const* d_in, const int* in_sizes, int n_in,
                              void* d_out, int out_size, void* d_ws, size_t ws_size,
                              hipStream_t stream) {
    const float* sem   = (const float*)d_in[0];
    const float* x     = (const float*)d_in[1];
    const int*   ei    = (const int*)d_in[2];
    const int*   batch = (const int*)d_in[3];
    const int* src = ei;
    const int* dst = ei + NE;

    const float* c1W1 = (const float*)d_in[4];
    const float* c1b1 = (const float*)d_in[5];
    const float* c1W2 = (const float*)d_in[6];
    const float* c1b2 = (const float*)d_in[7];
    const float* c2W1 = (const float*)d_in[8];
    const float* c2b1 = (const float*)d_in[9];
    const float* c2W2 = (const float*)d_in[10];
    const float* c2b2 = (const float*)d_in[11];
    const float* c3W1 = (const float*)d_in[12];
    const float* c3b1 = (const float*)d_in[13];
    const float* c3W2 = (const float*)d_in[14];
    const float* c3b2 = (const float*)d_in[15];
    const float* bn1g = (const float*)d_in[16];
    const float* bn1b = (const float*)d_in[17];
    const float* bn2g = (const float*)d_in[18];
    const float* bn2b = (const float*)d_in[19];
    const float* bn3g = (const float*)d_in[20];
    const float* bn3b = (const float*)d_in[21];
    const float* Ws   = (const float*)d_in[22];
    const float* bs_  = (const float*)d_in[23];
    const float* Wg   = (const float*)d_in[24];
    const float* bg   = (const float*)d_in[25];
    const float* Wq   = (const float*)d_in[26];
    const float* Wk   = (const float*)d_in[27];
    const float* Wv   = (const float*)d_in[28];
    const float* Wc1  = (const float*)d_in[29];
    const float* bc1  = (const float*)d_in[30];
    const float* Wc2  = (const float*)d_in[31];
    const float* bc2  = (const float*)d_in[32];

    // workspace layout
    float* P  = (float*)d_ws;
    float* Q  = P + (size_t)NN * DH;
    float* R  = Q + (size_t)NN * DH;
    float* gf = R + (size_t)NN * DH;
    int* counts  = (int*)(gf + (size_t)NB * DH);
    int* offsets = counts + NN;
    int* cursor  = offsets + NN;
    int* excl    = cursor + NN;
    int* bsums   = excl + NN;
    int* eidx    = bsums + 128;

    const int gemm_grid = (NN + 127) / 128;
    const int agg_grid  = (NN + 3) / 4;
    const int edge_grid = (NE + 255) / 256;

    // ---- CSR build (once per call, reused by all 3 layers) ----
    zero_counts<<<SCAN_NBLK, 1024, 0, stream>>>(counts);
    hist_kernel<<<edge_grid, 256, 0, stream>>>(dst, counts);
    scan1<<<SCAN_NBLK, 1024, 0, stream>>>(counts, excl, bsums);
    scan2<<<1, 128, 0, stream>>>(bsums, SCAN_NBLK);
    scan3<<<SCAN_NBLK, 1024, 0, stream>>>(excl, bsums, offsets, cursor);
    scatter_kernel<<<edge_grid, 256, 0, stream>>>(src, dst, cursor, eidx);

    // ---- layer 1 (input dim 78) ----
    agg_csr78<<<agg_grid, 256, 0, stream>>>(x, offsets, counts, eidx, P);
    gemm_epi<DIN, 0><<<gemm_grid, 256, 0, stream>>>(P, c1W1, c1b1, nullptr, nullptr, Q, NN);
    gemm_epi<DH, 1><<<gemm_grid, 256, 0, stream>>>(Q, c1W2, c1b2, bn1g, bn1b, R, NN);

    // ---- layer 2 ----
    agg_csr128<<<agg_grid, 256, 0, stream>>>(R, offsets, counts, eidx, P);
    gemm_epi<DH, 0><<<gemm_grid, 256, 0, stream>>>(P, c2W1, c2b1, nullptr, nullptr, Q, NN);
    gemm_epi<DH, 1><<<gemm_grid, 256, 0, stream>>>(Q, c2W2, c2b2, bn2g, bn2b, R, NN);

    // ---- layer 3 ----
    agg_csr128<<<agg_grid, 256, 0, stream>>>(R, offsets, counts, eidx, P);
    gemm_epi<DH, 0><<<gemm_grid, 256, 0, stream>>>(P, c3W1, c3b1, nullptr, nullptr, Q, NN);
    gemm_epi<DH, 1><<<gemm_grid, 256, 0, stream>>>(Q, c3W2, c3b2, bn3g, bn3b, R, NN);

    // ---- pool + fusion ----
    pool_kernel<<<NB, 1024, 0, stream>>>(R, batch, gf);
    fusion_kernel<<<NB, 1024, 0, stream>>>(sem, gf, Ws, bs_, Wg, bg, Wq, Wk, Wv,
                                           Wc1, bc1, Wc2, bc2, (float*)d_out);
}

// Round 8
// 818.909 us; speedup vs baseline: 1.5827x; 1.4940x over previous
//
#include <hip/hip_runtime.h>
#include <hip/hip_bf16.h>

#define NN 100000
#define NE 1600000
#define NB 64
#define DIN 78
#define DH 128
#define SD 768
#define FD 256
#define SCAN_NBLK 98   // ceil(NN/1024)

// 1/sqrt(1 + 1e-5)
#define BN_SCALE 0.9999950000374997f

typedef __attribute__((ext_vector_type(8))) short short8v;
typedef __attribute__((ext_vector_type(4))) float float4v;

__device__ __forceinline__ float bf2f(ushort u) {
    return __uint_as_float(((unsigned int)u) << 16);
}
__device__ __forceinline__ ushort f2bfu(float f) {
    __hip_bfloat16 h = __float2bfloat16(f);
    ushort u;
    __builtin_memcpy(&u, &h, 2);
    return u;
}

// ================= CSR build =================
__global__ void zero_counts(int* __restrict__ counts) {
    int i = blockIdx.x * 1024 + threadIdx.x;
    if (i < NN) counts[i] = 0;
}

__global__ void hist_kernel(const int* __restrict__ dst, int* __restrict__ counts) {
    int e = blockIdx.x * 256 + threadIdx.x;
    if (e < NE) atomicAdd(&counts[dst[e]], 1);
}

__global__ __launch_bounds__(1024) void scan1(const int* __restrict__ counts,
                                              int* __restrict__ excl,
                                              int* __restrict__ bsums) {
    __shared__ int tmp[1024];
    int tid = threadIdx.x;
    int i = blockIdx.x * 1024 + tid;
    int v = (i < NN) ? counts[i] : 0;
    tmp[tid] = v;
    __syncthreads();
#pragma unroll
    for (int off = 1; off < 1024; off <<= 1) {
        int t = (tid >= off) ? tmp[tid - off] : 0;
        __syncthreads();
        tmp[tid] += t;
        __syncthreads();
    }
    if (i < NN) excl[i] = tmp[tid] - v;
    if (tid == 1023) bsums[blockIdx.x] = tmp[1023];
}

__global__ __launch_bounds__(128) void scan2(int* __restrict__ bsums, int nb) {
    __shared__ int tmp[128];
    int tid = threadIdx.x;
    int v = (tid < nb) ? bsums[tid] : 0;
    tmp[tid] = v;
    __syncthreads();
#pragma unroll
    for (int off = 1; off < 128; off <<= 1) {
        int t = (tid >= off) ? tmp[tid - off] : 0;
        __syncthreads();
        tmp[tid] += t;
        __syncthreads();
    }
    if (tid < nb) bsums[tid] = tmp[tid] - v;
}

__global__ void scan3(const int* __restrict__ excl, const int* __restrict__ bsums,
                      int* __restrict__ offsets, int* __restrict__ cursor) {
    int i = blockIdx.x * 1024 + threadIdx.x;
    if (i < NN) {
        int v = excl[i] + bsums[blockIdx.x];
        offsets[i] = v;
        cursor[i] = v;
    }
}

__global__ void scatter_kernel(const int* __restrict__ src, const int* __restrict__ dst,
                               int* __restrict__ cursor, int* __restrict__ eidx) {
    int e = blockIdx.x * 256 + threadIdx.x;
    if (e < NE) {
        int p = atomicAdd(&cursor[dst[e]], 1);
        eidx[p] = src[e];
    }
}

// ================= gather aggregation =================
// Layer 1: reads x fp32 [NN][78], writes bf16 A0 [NN][96] (cols 78..95 zero).
__global__ __launch_bounds__(256) void agg_csr78(const float* __restrict__ x,
                                                 const int* __restrict__ off,
                                                 const int* __restrict__ cnt,
                                                 const int* __restrict__ eidx,
                                                 ushort* __restrict__ A0) {
    int node = blockIdx.x * 4 + (threadIdx.x >> 6);
    if (node >= NN) return;
    int lane = threadIdx.x & 63;
    bool act = lane < 39;
    int col = lane * 2;
    int start = off[node], deg = cnt[node];
    float2 sum = make_float2(0.f, 0.f);
    if (act) sum = *(const float2*)&x[(size_t)node * DIN + col];
    for (int base = 0; base < deg; base += 64) {
        int rem = deg - base;
        int m = rem < 64 ? rem : 64;
        int ev = (lane < m) ? eidx[start + base + lane] : 0;
#pragma unroll 4
        for (int j = 0; j < m; ++j) {
            int s = __shfl(ev, j);
            if (act) {
                float2 v = *(const float2*)&x[(size_t)s * DIN + col];
                sum.x += v.x;
                sum.y += v.y;
            }
        }
    }
    if (lane < 48) {
        ushort2 o;
        o.x = act ? f2bfu(sum.x) : (ushort)0;
        o.y = act ? f2bfu(sum.y) : (ushort)0;
        *(ushort2*)&A0[(size_t)node * 96 + col] = o;
    }
}

// Layers 2/3: h bf16 [NN][128] -> z bf16 [NN][128]; fp32 accumulate.
// Half-wave (32 lanes x ushort4 = 256B) per neighbor row; 2 rows in flight per wave.
__global__ __launch_bounds__(256) void agg_csr128(const ushort* __restrict__ h,
                                                  const int* __restrict__ off,
                                                  const int* __restrict__ cnt,
                                                  const int* __restrict__ eidx,
                                                  ushort* __restrict__ z) {
    int node = blockIdx.x * 4 + (threadIdx.x >> 6);
    if (node >= NN) return;
    int lane = threadIdx.x & 63;
    int half = lane >> 5;
    int colq = (lane & 31);          // ushort4 index (4 bf16 = 8B)
    int start = off[node], deg = cnt[node];
    float4 sum = make_float4(0.f, 0.f, 0.f, 0.f);
    if (half == 0) {
        ushort4 v = *(const ushort4*)&h[(size_t)node * DH + colq * 4];
        sum.x = bf2f(v.x); sum.y = bf2f(v.y); sum.z = bf2f(v.z); sum.w = bf2f(v.w);
    }
    for (int base = 0; base < deg; base += 64) {
        int rem = deg - base;
        int m = rem < 64 ? rem : 64;
        int ev = (lane < m) ? eidx[start + base + lane] : 0;
#pragma unroll 2
        for (int j = half; j < m; j += 2) {
            int s = __shfl(ev, j);
            ushort4 v = *(const ushort4*)&h[(size_t)s * DH + colq * 4];
            sum.x += bf2f(v.x); sum.y += bf2f(v.y);
            sum.z += bf2f(v.z); sum.w += bf2f(v.w);
        }
    }
    sum.x += __shfl_xor(sum.x, 32);
    sum.y += __shfl_xor(sum.y, 32);
    sum.z += __shfl_xor(sum.z, 32);
    sum.w += __shfl_xor(sum.w, 32);
    if (half == 0) {
        ushort4 o;
        o.x = f2bfu(sum.x); o.y = f2bfu(sum.y);
        o.z = f2bfu(sum.z); o.w = f2bfu(sum.w);
        *(ushort4*)&z[(size_t)node * DH + colq * 4] = o;
    }
}

// ================= MFMA GEMM =================
// C[M,128] = epi(A[M,KA]_bf16 @ W[KW,128]_fp32->bf16)
// 128x128 tile, 4 waves (2x2), each wave 4x4 16x16 subtiles, K-step 32.
// LDS layout [kchunk(4)][row/col(128)][8 bf16] -> frag reads are 16B stride (free).
// EPI 0: relu(+bias); EPI 1: relu((+bias)*g*BN_SCALE + bb). Output bf16.
template <int KA, int KW, int EPI>
__global__ __launch_bounds__(256) void gemm_mfma(
        const ushort* __restrict__ A, const float* __restrict__ W,
        const float* __restrict__ bias, const float* __restrict__ g,
        const float* __restrict__ bb, ushort* __restrict__ C, int nrows) {
    constexpr int KSTEPS = KA / 32;
    __shared__ ushort Asl[4][128][8];
    __shared__ ushort Bsl[4][128][8];
    const int tid = threadIdx.x;
    const int wave = tid >> 6, lane = tid & 63;
    const int wm = wave >> 1, wn = wave & 1;
    const int r0 = blockIdx.x * 128;
    const int lhi = lane >> 4;       // 0..3 : kchunk for frags
    const int llo = lane & 15;

    float4v acc[4][4];
#pragma unroll
    for (int i = 0; i < 4; ++i)
#pragma unroll
        for (int j = 0; j < 4; ++j) acc[i][j] = (float4v){0.f, 0.f, 0.f, 0.f};

    for (int kt = 0; kt < KSTEPS; ++kt) {
        // ---- stage A: 512 (row,kc) pairs, 16B each ----
#pragma unroll
        for (int p = tid; p < 512; p += 256) {
            int row = p >> 2, kc = p & 3;
            int grow = r0 + row;
            uint4 v = make_uint4(0u, 0u, 0u, 0u);
            if (grow < nrows)
                v = *(const uint4*)&A[(size_t)grow * KA + kt * 32 + kc * 8];
            *(uint4*)&Asl[kc][row][0] = v;
        }
        // ---- stage B: 512 (col,kc) pairs; convert fp32 W -> bf16 ----
#pragma unroll
        for (int p = tid; p < 512; p += 256) {
            int col = p & 127, kc = p >> 7;
            ushort tmp[8];
#pragma unroll
            for (int j = 0; j < 8; ++j) {
                int kk = kt * 32 + kc * 8 + j;
                float wv = (kk < KW) ? W[(size_t)kk * 128 + col] : 0.f;
                tmp[j] = f2bfu(wv);
            }
            *(uint4*)&Bsl[kc][col][0] = *(uint4*)&tmp[0];
        }
        __syncthreads();

        short8v av[4], bv[4];
#pragma unroll
        for (int s = 0; s < 4; ++s) {
            av[s] = *(const short8v*)&Asl[lhi][wm * 64 + s * 16 + llo][0];
            bv[s] = *(const short8v*)&Bsl[lhi][wn * 64 + s * 16 + llo][0];
        }
#pragma unroll
        for (int sm = 0; sm < 4; ++sm)
#pragma unroll
            for (int sn = 0; sn < 4; ++sn)
                acc[sm][sn] = __builtin_amdgcn_mfma_f32_16x16x32_bf16(
                    av[sm], bv[sn], acc[sm][sn], 0, 0, 0);
        __syncthreads();
    }

    // ---- epilogue: row=(lane>>4)*4+reg, col=lane&15 within subtile ----
#pragma unroll
    for (int sm = 0; sm < 4; ++sm) {
#pragma unroll
        for (int reg = 0; reg < 4; ++reg) {
            int row = r0 + wm * 64 + sm * 16 + lhi * 4 + reg;
            if (row >= nrows) continue;
#pragma unroll
            for (int sn = 0; sn < 4; ++sn) {
                int col = wn * 64 + sn * 16 + llo;
                float v = acc[sm][sn][reg] + bias[col];
                if constexpr (EPI == 1) {
                    v = v * (g[col] * BN_SCALE) + bb[col];
                }
                v = fmaxf(v, 0.f);
                C[(size_t)row * 128 + col] = f2bfu(v);
            }
        }
    }
}

// ================= global mean pool (bf16 in, fp32 out) =================
__device__ __forceinline__ int lower_bound_i(const int* a, int n, int v) {
    int lo = 0, hi = n;
    while (lo < hi) {
        int m = (lo + hi) >> 1;
        if (a[m] < v) lo = m + 1; else hi = m;
    }
    return lo;
}

__global__ __launch_bounds__(1024) void pool_kernel(const ushort* __restrict__ h,
                                                    const int* __restrict__ batch,
                                                    float* __restrict__ gf) {
    int b = blockIdx.x;
    int f = threadIdx.x & 127;
    int chunk = threadIdx.x >> 7;   // 0..7
    __shared__ float part[8][DH];
    int lo = lower_bound_i(batch, NN, b);
    int hi = lower_bound_i(batch, NN, b + 1);
    float sum = 0.f;
    for (int i = lo + chunk; i < hi; i += 8) sum += bf2f(h[(size_t)i * DH + f]);
    part[chunk][f] = sum;
    __syncthreads();
    if (chunk == 0) {
        float s = part[0][f] + part[1][f] + part[2][f] + part[3][f] +
                  part[4][f] + part[5][f] + part[6][f] + part[7][f];
        int cnt = hi - lo;
        gf[b * DH + f] = s / (float)(cnt > 0 ? cnt : 1);
    }
}

// ================= fusion + attention + classifier (fp32) =================
__global__ __launch_bounds__(1024) void fusion_kernel(
        const float* __restrict__ sem, const float* __restrict__ gf,
        const float* __restrict__ Ws, const float* __restrict__ bs,
        const float* __restrict__ Wg, const float* __restrict__ bg,
        const float* __restrict__ Wq, const float* __restrict__ Wk,
        const float* __restrict__ Wv,
        const float* __restrict__ Wc1, const float* __restrict__ bc1,
        const float* __restrict__ Wc2, const float* __restrict__ bc2,
        float* __restrict__ out) {
    int b = blockIdx.x;
    int tid = threadIdx.x;      // 1024
    int c = tid & 255;
    int kc = tid >> 8;          // 0..3
    __shared__ float tok[2][FD];
    __shared__ float part[4][FD];
    __shared__ float qv[6][FD]; // q0 q1 k0 k1 v0 v1
    __shared__ float att[4];
    __shared__ float fused[FD];
    __shared__ float c1s[FD / 2];

    {
        const float* sr = &sem[(size_t)b * SD];
        float acc = 0.f;
#pragma unroll 8
        for (int k = kc * 192; k < (kc + 1) * 192; ++k)
            acc = fmaf(sr[k], Ws[(size_t)k * FD + c], acc);
        part[kc][c] = acc;
    }
    __syncthreads();
    if (kc == 0)
        tok[0][c] = part[0][c] + part[1][c] + part[2][c] + part[3][c] + bs[c];
    __syncthreads();

    {
        const float* gr = &gf[(size_t)b * DH];
        float acc = 0.f;
#pragma unroll 8
        for (int k = kc * 32; k < (kc + 1) * 32; ++k)
            acc = fmaf(gr[k], Wg[(size_t)k * FD + c], acc);
        part[kc][c] = acc;
    }
    __syncthreads();
    if (kc == 0)
        tok[1][c] = part[0][c] + part[1][c] + part[2][c] + part[3][c] + bg[c];
    __syncthreads();

#pragma unroll
    for (int m = 0; m < 6; ++m) {
        const float* Wm = (m < 2) ? Wq : ((m < 4) ? Wk : Wv);
        int t = m & 1;
        float acc = 0.f;
#pragma unroll 8
        for (int k = kc * 64; k < (kc + 1) * 64; ++k)
            acc = fmaf(tok[t][k], Wm[(size_t)k * FD + c], acc);
        part[kc][c] = acc;
        __syncthreads();
        if (kc == 0)
            qv[m][c] = part[0][c] + part[1][c] + part[2][c] + part[3][c];
        __syncthreads();
    }

    if (tid < 256) {
        int w = tid >> 6;
        int lane = tid & 63;
        int qi = w >> 1, ki = w & 1;
        float s = 0.f;
#pragma unroll
        for (int k = lane; k < FD; k += 64) s += qv[qi][k] * qv[2 + ki][k];
#pragma unroll
        for (int d = 1; d < 64; d <<= 1) s += __shfl_xor(s, d);
        if (lane == 0) att[w] = s * (1.0f / 16.0f);
    }
    __syncthreads();
    if (tid < 2) {
        float a0 = att[tid * 2], a1 = att[tid * 2 + 1];
        float mx = fmaxf(a0, a1);
        float e0 = __expf(a0 - mx), e1 = __expf(a1 - mx);
        float inv = 1.f / (e0 + e1);
        att[tid * 2] = e0 * inv;
        att[tid * 2 + 1] = e1 * inv;
    }
    __syncthreads();

    if (kc == 0)
        fused[c] = 0.5f * ((att[0] + att[2]) * qv[4][c] + (att[1] + att[3]) * qv[5][c]);
    __syncthreads();

    {
        float* pf = &part[0][0];   // flat [1024]
        int cc = tid & 127;
        int k2 = tid >> 7;          // 0..7
        float acc = 0.f;
#pragma unroll 8
        for (int k = k2 * 32; k < (k2 + 1) * 32; ++k)
            acc = fmaf(fused[k], Wc1[(size_t)k * (FD / 2) + cc], acc);
        pf[tid] = acc;
        __syncthreads();
        if (tid < 128) {
            float s = 0.f;
#pragma unroll
            for (int j = 0; j < 8; ++j) s += pf[j * 128 + tid];
            c1s[tid] = fmaxf(s + bc1[tid], 0.f);
        }
    }
    __syncthreads();

    if (tid < 128) {
        int w = tid >> 6;
        int lane = tid & 63;
        float s = c1s[lane] * Wc2[(size_t)lane * 2 + w] +
                  c1s[lane + 64] * Wc2[(size_t)(lane + 64) * 2 + w];
#pragma unroll
        for (int d = 1; d < 64; d <<= 1) s += __shfl_xor(s, d);
        if (lane == 0) out[b * 2 + w] = s + bc2[w];
    }
}

// ================= launch =================
extern "C" void kernel_launch(void* const* d_in, const int* in_sizes, int n_in,
                              void* d_out, int out_size, void* d_ws, size_t ws_size,
                              hipStream_t stream) {
    const float* sem   = (const float*)d_in[0];
    const float* x     = (const float*)d_in[1];
    const int*   ei    = (const int*)d_in[2];
    const int*   batch = (const int*)d_in[3];
    const int* src = ei;
    const int* dst = ei + NE;

    const float* c1W1 = (const float*)d_in[4];
    const float* c1b1 = (const float*)d_in[5];
    const float* c1W2 = (const float*)d_in[6];
    const float* c1b2 = (const float*)d_in[7];
    const float* c2W1 = (const float*)d_in[8];
    const float* c2b1 = (const float*)d_in[9];
    const float* c2W2 = (const float*)d_in[10];
    const float* c2b2 = (const float*)d_in[11];
    const float* c3W1 = (const float*)d_in[12];
    const float* c3b1 = (const float*)d_in[13];
    const float* c3W2 = (const float*)d_in[14];
    const float* c3b2 = (const float*)d_in[15];
    const float* bn1g = (const float*)d_in[16];
    const float* bn1b = (const float*)d_in[17];
    const float* bn2g = (const float*)d_in[18];
    const float* bn2b = (const float*)d_in[19];
    const float* bn3g = (const float*)d_in[20];
    const float* bn3b = (const float*)d_in[21];
    const float* Ws   = (const float*)d_in[22];
    const float* bs_  = (const float*)d_in[23];
    const float* Wg   = (const float*)d_in[24];
    const float* bg   = (const float*)d_in[25];
    const float* Wq   = (const float*)d_in[26];
    const float* Wk   = (const float*)d_in[27];
    const float* Wv   = (const float*)d_in[28];
    const float* Wc1  = (const float*)d_in[29];
    const float* bc1  = (const float*)d_in[30];
    const float* Wc2  = (const float*)d_in[31];
    const float* bc2  = (const float*)d_in[32];

    // workspace layout (bf16 intermediates)
    ushort* A0 = (ushort*)d_ws;                   // [NN][96]
    ushort* P  = A0 + (size_t)NN * 96;            // [NN][128]
    ushort* Q  = P + (size_t)NN * DH;             // [NN][128]
    ushort* R  = Q + (size_t)NN * DH;             // [NN][128]
    float* gf  = (float*)(R + (size_t)NN * DH);   // [NB][128]
    int* counts  = (int*)(gf + (size_t)NB * DH);
    int* offsets = counts + NN;
    int* cursor  = offsets + NN;
    int* excl    = cursor + NN;
    int* bsums   = excl + NN;
    int* eidx    = bsums + 128;

    const int gemm_grid = (NN + 127) / 128;
    const int agg_grid  = (NN + 3) / 4;
    const int edge_grid = (NE + 255) / 256;

    // ---- CSR build (once per call, reused by all 3 layers) ----
    zero_counts<<<SCAN_NBLK, 1024, 0, stream>>>(counts);
    hist_kernel<<<edge_grid, 256, 0, stream>>>(dst, counts);
    scan1<<<SCAN_NBLK, 1024, 0, stream>>>(counts, excl, bsums);
    scan2<<<1, 128, 0, stream>>>(bsums, SCAN_NBLK);
    scan3<<<SCAN_NBLK, 1024, 0, stream>>>(excl, bsums, offsets, cursor);
    scatter_kernel<<<edge_grid, 256, 0, stream>>>(src, dst, cursor, eidx);

    // ---- layer 1 (K=78 padded to 96) ----
    agg_csr78<<<agg_grid, 256, 0, stream>>>(x, offsets, counts, eidx, A0);
    gemm_mfma<96, 78, 0><<<gemm_grid, 256, 0, stream>>>(A0, c1W1, c1b1, nullptr, nullptr, Q, NN);
    gemm_mfma<128, 128, 1><<<gemm_grid, 256, 0, stream>>>(Q, c1W2, c1b2, bn1g, bn1b, R, NN);

    // ---- layer 2 ----
    agg_csr128<<<agg_grid, 256, 0, stream>>>(R, offsets, counts, eidx, P);
    gemm_mfma<128, 128, 0><<<gemm_grid, 256, 0, stream>>>(P, c2W1, c2b1, nullptr, nullptr, Q, NN);
    gemm_mfma<128, 128, 1><<<gemm_grid, 256, 0, stream>>>(Q, c2W2, c2b2, bn2g, bn2b, R, NN);

    // ---- layer 3 ----
    agg_csr128<<<agg_grid, 256, 0, stream>>>(R, offsets, counts, eidx, P);
    gemm_mfma<128, 128, 0><<<gemm_grid, 256, 0, stream>>>(P, c3W1, c3b1, nullptr, nullptr, Q, NN);
    gemm_mfma<128, 128, 1><<<gemm_grid, 256, 0, stream>>>(Q, c3W2, c3b2, bn3g, bn3b, R, NN);

    // ---- pool + fusion ----
    pool_kernel<<<NB, 1024, 0, stream>>>(R, batch, gf);
    fusion_kernel<<<NB, 1024, 0, stream>>>(sem, gf, Ws, bs_, Wg, bg, Wq, Wk, Wv,
                                           Wc1, bc1, Wc2, bc2, (float*)d_out);
}

// Round 9
// 754.882 us; speedup vs baseline: 1.7169x; 1.0848x over previous
//
#include <hip/hip_runtime.h>
#include <hip/hip_bf16.h>

#define NN 100000
#define NE 1600000
#define NB 64
#define DIN 78
#define DH 128
#define SD 768
#define FD 256
#define SCAN_NBLK 98   // ceil(NN/1024)

// 1/sqrt(1 + 1e-5)
#define BN_SCALE 0.9999950000374997f

typedef __attribute__((ext_vector_type(8))) short short8v;
typedef __attribute__((ext_vector_type(8))) unsigned short ushort8v;
typedef __attribute__((ext_vector_type(4))) float float4v;

__device__ __forceinline__ float bf2f(ushort u) {
    return __uint_as_float(((unsigned int)u) << 16);
}
__device__ __forceinline__ ushort f2bfu(float f) {
    __hip_bfloat16 h = __float2bfloat16(f);
    ushort u;
    __builtin_memcpy(&u, &h, 2);
    return u;
}

// ================= CSR build =================
__global__ void zero_counts(int* __restrict__ counts) {
    int i = blockIdx.x * 1024 + threadIdx.x;
    if (i < NN) counts[i] = 0;
}

__global__ void hist_kernel(const int* __restrict__ dst, int* __restrict__ counts) {
    int e = blockIdx.x * 256 + threadIdx.x;
    if (e < NE) atomicAdd(&counts[dst[e]], 1);
}

__global__ __launch_bounds__(1024) void scan1(const int* __restrict__ counts,
                                              int* __restrict__ excl,
                                              int* __restrict__ bsums) {
    __shared__ int tmp[1024];
    int tid = threadIdx.x;
    int i = blockIdx.x * 1024 + tid;
    int v = (i < NN) ? counts[i] : 0;
    tmp[tid] = v;
    __syncthreads();
#pragma unroll
    for (int off = 1; off < 1024; off <<= 1) {
        int t = (tid >= off) ? tmp[tid - off] : 0;
        __syncthreads();
        tmp[tid] += t;
        __syncthreads();
    }
    if (i < NN) excl[i] = tmp[tid] - v;
    if (tid == 1023) bsums[blockIdx.x] = tmp[1023];
}

__global__ __launch_bounds__(128) void scan2(int* __restrict__ bsums, int nb) {
    __shared__ int tmp[128];
    int tid = threadIdx.x;
    int v = (tid < nb) ? bsums[tid] : 0;
    tmp[tid] = v;
    __syncthreads();
#pragma unroll
    for (int off = 1; off < 128; off <<= 1) {
        int t = (tid >= off) ? tmp[tid - off] : 0;
        __syncthreads();
        tmp[tid] += t;
        __syncthreads();
    }
    if (tid < nb) bsums[tid] = tmp[tid] - v;
}

__global__ void scan3(const int* __restrict__ excl, const int* __restrict__ bsums,
                      int* __restrict__ offsets, int* __restrict__ cursor) {
    int i = blockIdx.x * 1024 + threadIdx.x;
    if (i < NN) {
        int v = excl[i] + bsums[blockIdx.x];
        offsets[i] = v;
        cursor[i] = v;
    }
}

// 8-pass dst-range-partitioned scatter: all 2048 blocks co-resident (8/CU),
// each pass writes a ~800KB window of eidx -> lines get ~16 hits in L2.
__global__ __launch_bounds__(256) void scatter8(const int* __restrict__ src,
                                                const int* __restrict__ dst,
                                                int* __restrict__ cursor,
                                                int* __restrict__ eidx) {
    const int stride = 2048 * 256;
    int base = blockIdx.x * 256 + threadIdx.x;
#pragma unroll 1
    for (int p = 0; p < 8; ++p) {
        int dlo = p * (NN / 8);
        int dhi = (p == 7) ? NN : (p + 1) * (NN / 8);
#pragma unroll 1
        for (int e = base; e < NE; e += stride) {
            int d = dst[e];
            if (d >= dlo && d < dhi) {
                int q = atomicAdd(&cursor[d], 1);
                eidx[q] = src[e];
            }
        }
    }
}

// ================= x -> bf16 padded [NN][128] =================
__global__ __launch_bounds__(256) void xcast(const float* __restrict__ x,
                                             ushort* __restrict__ xb) {
    int node = blockIdx.x * 4 + (threadIdx.x >> 6);
    if (node >= NN) return;
    int lane = threadIdx.x & 63;
    int col = lane * 2;
    ushort2 o = make_ushort2(0, 0);
    if (lane < 39) {
        float2 v = *(const float2*)&x[(size_t)node * DIN + col];
        o.x = f2bfu(v.x);
        o.y = f2bfu(v.y);
    }
    *(ushort2*)&xb[(size_t)node * DH + col] = o;
}

// ================= weight prep: fp32 [KW][128] -> bf16 GEMM-ready =================
// Wt layout: [kt(4)][kc(4)][col(128)][j(8)]  (kk = kt*32+kc*8+j; zero for kk>=KW)
__global__ __launch_bounds__(256) void wprep(const float* __restrict__ W, int KW,
                                             ushort* __restrict__ Wt) {
    int t = blockIdx.x * 256 + threadIdx.x;   // 2048 total
    if (t >= 2048) return;
    int kt = t >> 9, kc = (t >> 7) & 3, col = t & 127;
    ushort tmp[8];
#pragma unroll
    for (int j = 0; j < 8; ++j) {
        int kk = kt * 32 + kc * 8 + j;
        tmp[j] = (kk < KW) ? f2bfu(W[(size_t)kk * 128 + col]) : (ushort)0;
    }
    *(uint4*)&Wt[(size_t)t * 8] = *(uint4*)&tmp[0];
}

// ================= gather aggregation (bf16 [NN][128]) =================
// z[n] = h[n] + sum_{neighbors}; quarter-wave (16 lanes x ushort8 = 256B) per
// neighbor row -> 4 rows in flight per wave; fp32 accumulate.
__global__ __launch_bounds__(256) void agg128(const ushort* __restrict__ h,
                                              const int* __restrict__ off,
                                              const int* __restrict__ cnt,
                                              const int* __restrict__ eidx,
                                              ushort* __restrict__ z) {
    int node = blockIdx.x * 4 + (threadIdx.x >> 6);
    if (node >= NN) return;
    int lane = threadIdx.x & 63;
    int q = lane >> 4;           // quarter-wave id: neighbor j % 4
    int llo = lane & 15;         // ushort8 index within row
    int start = off[node], deg = cnt[node];

    float acc[8];
#pragma unroll
    for (int i = 0; i < 8; ++i) acc[i] = 0.f;
    if (q == 0) {
        ushort8v v = *(const ushort8v*)&h[(size_t)node * DH + llo * 8];
#pragma unroll
        for (int i = 0; i < 8; ++i) acc[i] = bf2f(v[i]);
    }

    for (int base = 0; base < deg; base += 64) {
        int rem = deg - base;
        int m = rem < 64 ? rem : 64;
        int ev = (lane < m) ? eidx[start + base + lane] : 0;
#pragma unroll 4
        for (int j = q; j < m; j += 4) {
            int s = __shfl(ev, j);
            ushort8v v = *(const ushort8v*)&h[(size_t)s * DH + llo * 8];
#pragma unroll
            for (int i = 0; i < 8; ++i) acc[i] += bf2f(v[i]);
        }
    }

    // reduce across the 4 quarter-waves (lane bits 4 and 5)
#pragma unroll
    for (int i = 0; i < 8; ++i) {
        acc[i] += __shfl_xor(acc[i], 16);
        acc[i] += __shfl_xor(acc[i], 32);
    }
    if (q == 0) {
        ushort8v o;
#pragma unroll
        for (int i = 0; i < 8; ++i) o[i] = f2bfu(acc[i]);
        *(ushort8v*)&z[(size_t)node * DH + llo * 8] = o;
    }
}

// ================= MFMA GEMM =================
// C[M,128] = epi(A[M,128]_bf16 @ Wt_bf16)  K=128 (4 steps of 32).
// 128x128 tile, 4 waves (2x2), each wave 4x4 16x16 subtiles.
// EPI 0: relu(+bias); EPI 1: relu((+bias)*g*BN_SCALE + bb). Output bf16.
template <int EPI>
__global__ __launch_bounds__(256) void gemm_mfma(
        const ushort* __restrict__ A, const ushort* __restrict__ Wt,
        const float* __restrict__ bias, const float* __restrict__ g,
        const float* __restrict__ bb, ushort* __restrict__ C, int nrows) {
    __shared__ ushort Asl[4][128][8];
    __shared__ ushort Bsl[4][128][8];
    const int tid = threadIdx.x;
    const int wave = tid >> 6, lane = tid & 63;
    const int wm = wave >> 1, wn = wave & 1;
    const int r0 = blockIdx.x * 128;
    const int lhi = lane >> 4;       // 0..3 : kchunk for frags
    const int llo = lane & 15;

    float4v acc[4][4];
#pragma unroll
    for (int i = 0; i < 4; ++i)
#pragma unroll
        for (int j = 0; j < 4; ++j) acc[i][j] = (float4v){0.f, 0.f, 0.f, 0.f};

    const uint4* Wtv = (const uint4*)Wt;

    for (int kt = 0; kt < 4; ++kt) {
        // ---- stage A: 512 (row,kc) pairs, 16B each ----
#pragma unroll
        for (int p = tid; p < 512; p += 256) {
            int row = p >> 2, kc = p & 3;
            int grow = r0 + row;
            uint4 v = make_uint4(0u, 0u, 0u, 0u);
            if (grow < nrows)
                v = *(const uint4*)&A[(size_t)grow * DH + kt * 32 + kc * 8];
            *(uint4*)&Asl[kc][row][0] = v;
        }
        // ---- stage B: contiguous uint4 copy from pre-swizzled Wt ----
#pragma unroll
        for (int p = tid; p < 512; p += 256) {
            *(uint4*)&Bsl[0][0][p * 8] = Wtv[kt * 512 + p];
        }
        __syncthreads();

        short8v av[4], bv[4];
#pragma unroll
        for (int s = 0; s < 4; ++s) {
            av[s] = *(const short8v*)&Asl[lhi][wm * 64 + s * 16 + llo][0];
            bv[s] = *(const short8v*)&Bsl[lhi][wn * 64 + s * 16 + llo][0];
        }
#pragma unroll
        for (int sm = 0; sm < 4; ++sm)
#pragma unroll
            for (int sn = 0; sn < 4; ++sn)
                acc[sm][sn] = __builtin_amdgcn_mfma_f32_16x16x32_bf16(
                    av[sm], bv[sn], acc[sm][sn], 0, 0, 0);
        __syncthreads();
    }

    // ---- epilogue: row=(lane>>4)*4+reg, col=lane&15 within subtile ----
#pragma unroll
    for (int sm = 0; sm < 4; ++sm) {
#pragma unroll
        for (int reg = 0; reg < 4; ++reg) {
            int row = r0 + wm * 64 + sm * 16 + lhi * 4 + reg;
            if (row >= nrows) continue;
#pragma unroll
            for (int sn = 0; sn < 4; ++sn) {
                int col = wn * 64 + sn * 16 + llo;
                float v = acc[sm][sn][reg] + bias[col];
                if constexpr (EPI == 1) {
                    v = v * (g[col] * BN_SCALE) + bb[col];
                }
                v = fmaxf(v, 0.f);
                C[(size_t)row * 128 + col] = f2bfu(v);
            }
        }
    }
}

// ================= global mean pool (bf16 in, fp32 out) =================
__device__ __forceinline__ int lower_bound_i(const int* a, int n, int v) {
    int lo = 0, hi = n;
    while (lo < hi) {
        int m = (lo + hi) >> 1;
        if (a[m] < v) lo = m + 1; else hi = m;
    }
    return lo;
}

__global__ __launch_bounds__(1024) void pool_kernel(const ushort* __restrict__ h,
                                                    const int* __restrict__ batch,
                                                    float* __restrict__ gf) {
    int b = blockIdx.x;
    int f = threadIdx.x & 127;
    int chunk = threadIdx.x >> 7;   // 0..7
    __shared__ float part[8][DH];
    int lo = lower_bound_i(batch, NN, b);
    int hi = lower_bound_i(batch, NN, b + 1);
    float sum = 0.f;
    for (int i = lo + chunk; i < hi; i += 8) sum += bf2f(h[(size_t)i * DH + f]);
    part[chunk][f] = sum;
    __syncthreads();
    if (chunk == 0) {
        float s = part[0][f] + part[1][f] + part[2][f] + part[3][f] +
                  part[4][f] + part[5][f] + part[6][f] + part[7][f];
        int cnt = hi - lo;
        gf[b * DH + f] = s / (float)(cnt > 0 ? cnt : 1);
    }
}

// ================= fusion + attention + classifier (fp32) =================
__global__ __launch_bounds__(1024) void fusion_kernel(
        const float* __restrict__ sem, const float* __restrict__ gf,
        const float* __restrict__ Ws, const float* __restrict__ bs,
        const float* __restrict__ Wg, const float* __restrict__ bg,
        const float* __restrict__ Wq, const float* __restrict__ Wk,
        const float* __restrict__ Wv,
        const float* __restrict__ Wc1, const float* __restrict__ bc1,
        const float* __restrict__ Wc2, const float* __restrict__ bc2,
        float* __restrict__ out) {
    int b = blockIdx.x;
    int tid = threadIdx.x;      // 1024
    int c = tid & 255;
    int kc = tid >> 8;          // 0..3
    __shared__ float tok[2][FD];
    __shared__ float part[4][FD];
    __shared__ float qv[6][FD]; // q0 q1 k0 k1 v0 v1
    __shared__ float att[4];
    __shared__ float fused[FD];
    __shared__ float c1s[FD / 2];

    {
        const float* sr = &sem[(size_t)b * SD];
        float acc = 0.f;
#pragma unroll 8
        for (int k = kc * 192; k < (kc + 1) * 192; ++k)
            acc = fmaf(sr[k], Ws[(size_t)k * FD + c], acc);
        part[kc][c] = acc;
    }
    __syncthreads();
    if (kc == 0)
        tok[0][c] = part[0][c] + part[1][c] + part[2][c] + part[3][c] + bs[c];
    __syncthreads();

    {
        const float* gr = &gf[(size_t)b * DH];
        float acc = 0.f;
#pragma unroll 8
        for (int k = kc * 32; k < (kc + 1) * 32; ++k)
            acc = fmaf(gr[k], Wg[(size_t)k * FD + c], acc);
        part[kc][c] = acc;
    }
    __syncthreads();
    if (kc == 0)
        tok[1][c] = part[0][c] + part[1][c] + part[2][c] + part[3][c] + bg[c];
    __syncthreads();

#pragma unroll
    for (int m = 0; m < 6; ++m) {
        const float* Wm = (m < 2) ? Wq : ((m < 4) ? Wk : Wv);
        int t = m & 1;
        float acc = 0.f;
#pragma unroll 8
        for (int k = kc * 64; k < (kc + 1) * 64; ++k)
            acc = fmaf(tok[t][k], Wm[(size_t)k * FD + c], acc);
        part[kc][c] = acc;
        __syncthreads();
        if (kc == 0)
            qv[m][c] = part[0][c] + part[1][c] + part[2][c] + part[3][c];
        __syncthreads();
    }

    if (tid < 256) {
        int w = tid >> 6;
        int lane = tid & 63;
        int qi = w >> 1, ki = w & 1;
        float s = 0.f;
#pragma unroll
        for (int k = lane; k < FD; k += 64) s += qv[qi][k] * qv[2 + ki][k];
#pragma unroll
        for (int d = 1; d < 64; d <<= 1) s += __shfl_xor(s, d);
        if (lane == 0) att[w] = s * (1.0f / 16.0f);
    }
    __syncthreads();
    if (tid < 2) {
        float a0 = att[tid * 2], a1 = att[tid * 2 + 1];
        float mx = fmaxf(a0, a1);
        float e0 = __expf(a0 - mx), e1 = __expf(a1 - mx);
        float inv = 1.f / (e0 + e1);
        att[tid * 2] = e0 * inv;
        att[tid * 2 + 1] = e1 * inv;
    }
    __syncthreads();

    if (kc == 0)
        fused[c] = 0.5f * ((att[0] + att[2]) * qv[4][c] + (att[1] + att[3]) * qv[5][c]);
    __syncthreads();

    {
        float* pf = &part[0][0];   // flat [1024]
        int cc = tid & 127;
        int k2 = tid >> 7;          // 0..7
        float acc = 0.f;
#pragma unroll 8
        for (int k = k2 * 32; k < (k2 + 1) * 32; ++k)
            acc = fmaf(fused[k], Wc1[(size_t)k * (FD / 2) + cc], acc);
        pf[tid] = acc;
        __syncthreads();
        if (tid < 128) {
            float s = 0.f;
#pragma unroll
            for (int j = 0; j < 8; ++j) s += pf[j * 128 + tid];
            c1s[tid] = fmaxf(s + bc1[tid], 0.f);
        }
    }
    __syncthreads();

    if (tid < 128) {
        int w = tid >> 6;
        int lane = tid & 63;
        float s = c1s[lane] * Wc2[(size_t)lane * 2 + w] +
                  c1s[lane + 64] * Wc2[(size_t)(lane + 64) * 2 + w];
#pragma unroll
        for (int d = 1; d < 64; d <<= 1) s += __shfl_xor(s, d);
        if (lane == 0) out[b * 2 + w] = s + bc2[w];
    }
}

// ================= launch =================
extern "C" void kernel_launch(void* const* d_in, const int* in_sizes, int n_in,
                              void* d_out, int out_size, void* d_ws, size_t ws_size,
                              hipStream_t stream) {
    const float* sem   = (const float*)d_in[0];
    const float* x     = (const float*)d_in[1];
    const int*   ei    = (const int*)d_in[2];
    const int*   batch = (const int*)d_in[3];
    const int* src = ei;
    const int* dst = ei + NE;

    const float* c1W1 = (const float*)d_in[4];
    const float* c1b1 = (const float*)d_in[5];
    const float* c1W2 = (const float*)d_in[6];
    const float* c1b2 = (const float*)d_in[7];
    const float* c2W1 = (const float*)d_in[8];
    const float* c2b1 = (const float*)d_in[9];
    const float* c2W2 = (const float*)d_in[10];
    const float* c2b2 = (const float*)d_in[11];
    const float* c3W1 = (const float*)d_in[12];
    const float* c3b1 = (const float*)d_in[13];
    const float* c3W2 = (const float*)d_in[14];
    const float* c3b2 = (const float*)d_in[15];
    const float* bn1g = (const float*)d_in[16];
    const float* bn1b = (const float*)d_in[17];
    const float* bn2g = (const float*)d_in[18];
    const float* bn2b = (const float*)d_in[19];
    const float* bn3g = (const float*)d_in[20];
    const float* bn3b = (const float*)d_in[21];
    const float* Ws   = (const float*)d_in[22];
    const float* bs_  = (const float*)d_in[23];
    const float* Wg   = (const float*)d_in[24];
    const float* bg   = (const float*)d_in[25];
    const float* Wq   = (const float*)d_in[26];
    const float* Wk   = (const float*)d_in[27];
    const float* Wv   = (const float*)d_in[28];
    const float* Wc1  = (const float*)d_in[29];
    const float* bc1  = (const float*)d_in[30];
    const float* Wc2  = (const float*)d_in[31];
    const float* bc2  = (const float*)d_in[32];

    // workspace layout (bf16 intermediates)
    ushort* xb = (ushort*)d_ws;                   // [NN][128]
    ushort* P  = xb + (size_t)NN * DH;            // [NN][128]
    ushort* Q  = P + (size_t)NN * DH;             // [NN][128]
    ushort* R  = Q + (size_t)NN * DH;             // [NN][128]
    ushort* Wt = R + (size_t)NN * DH;             // 6 x 16384
    float* gf  = (float*)(Wt + 6 * 16384);        // [NB][128]
    int* counts  = (int*)(gf + (size_t)NB * DH);
    int* offsets = counts + NN;
    int* cursor  = offsets + NN;
    int* excl    = cursor + NN;
    int* bsums   = excl + NN;
    int* eidx    = bsums + 128;

    ushort* Wt1 = Wt;
    ushort* Wt2 = Wt + 16384;
    ushort* Wt3 = Wt + 2 * 16384;
    ushort* Wt4 = Wt + 3 * 16384;
    ushort* Wt5 = Wt + 4 * 16384;
    ushort* Wt6 = Wt + 5 * 16384;

    const int gemm_grid = (NN + 127) / 128;
    const int agg_grid  = (NN + 3) / 4;
    const int edge_grid = (NE + 255) / 256;

    // ---- CSR build (once per call, reused by all 3 layers) ----
    zero_counts<<<SCAN_NBLK, 1024, 0, stream>>>(counts);
    hist_kernel<<<edge_grid, 256, 0, stream>>>(dst, counts);
    scan1<<<SCAN_NBLK, 1024, 0, stream>>>(counts, excl, bsums);
    scan2<<<1, 128, 0, stream>>>(bsums, SCAN_NBLK);
    scan3<<<SCAN_NBLK, 1024, 0, stream>>>(excl, bsums, offsets, cursor);
    scatter8<<<2048, 256, 0, stream>>>(src, dst, cursor, eidx);

    // ---- input cast + weight prep ----
    xcast<<<agg_grid, 256, 0, stream>>>(x, xb);
    wprep<<<8, 256, 0, stream>>>(c1W1, DIN, Wt1);
    wprep<<<8, 256, 0, stream>>>(c1W2, DH, Wt2);
    wprep<<<8, 256, 0, stream>>>(c2W1, DH, Wt3);
    wprep<<<8, 256, 0, stream>>>(c2W2, DH, Wt4);
    wprep<<<8, 256, 0, stream>>>(c3W1, DH, Wt5);
    wprep<<<8, 256, 0, stream>>>(c3W2, DH, Wt6);

    // ---- layer 1 ----
    agg128<<<agg_grid, 256, 0, stream>>>(xb, offsets, counts, eidx, P);
    gemm_mfma<0><<<gemm_grid, 256, 0, stream>>>(P, Wt1, c1b1, nullptr, nullptr, Q, NN);
    gemm_mfma<1><<<gemm_grid, 256, 0, stream>>>(Q, Wt2, c1b2, bn1g, bn1b, R, NN);

    // ---- layer 2 ----
    agg128<<<agg_grid, 256, 0, stream>>>(R, offsets, counts, eidx, P);
    gemm_mfma<0><<<gemm_grid, 256, 0, stream>>>(P, Wt3, c2b1, nullptr, nullptr, Q, NN);
    gemm_mfma<1><<<gemm_grid, 256, 0, stream>>>(Q, Wt4, c2b2, bn2g, bn2b, R, NN);

    // ---- layer 3 ----
    agg128<<<agg_grid, 256, 0, stream>>>(R, offsets, counts, eidx, P);
    gemm_mfma<0><<<gemm_grid, 256, 0, stream>>>(P, Wt5, c3b1, nullptr, nullptr, Q, NN);
    gemm_mfma<1><<<gemm_grid, 256, 0, stream>>>(Q, Wt6, c3b2, bn3g, bn3b, R, NN);

    // ---- pool + fusion ----
    pool_kernel<<<NB, 1024, 0, stream>>>(R, batch, gf);
    fusion_kernel<<<NB, 1024, 0, stream>>>(sem, gf, Ws, bs_, Wg, bg, Wq, Wk, Wv,
                                           Wc1, bc1, Wc2, bc2, (float*)d_out);
}